// Round 7
// baseline (609.220 us; speedup 1.0000x reference)
//
#include <hip/hip_runtime.h>
#include <hip/hip_bf16.h>
#include <stdint.h>

using bf16 = __hip_bfloat16;
typedef short bf16x8 __attribute__((ext_vector_type(8)));
typedef float floatx4 __attribute__((ext_vector_type(4)));

static constexpr int NODES = 2048;
static constexpr int EDGES = 32768;

// pack 8 consecutive f32 -> 8 bf16 (rne) as uint4
__device__ inline uint4 cvt8(const float* __restrict__ p) {
    const float4* f = (const float4*)p;
    float4 a = f[0], b = f[1];
    union { uint4 u; bf16 h[8]; } pk;
    pk.h[0] = __float2bfloat16(a.x); pk.h[1] = __float2bfloat16(a.y);
    pk.h[2] = __float2bfloat16(a.z); pk.h[3] = __float2bfloat16(a.w);
    pk.h[4] = __float2bfloat16(b.x); pk.h[5] = __float2bfloat16(b.y);
    pk.h[6] = __float2bfloat16(b.z); pk.h[7] = __float2bfloat16(b.w);
    return pk.u;
}

// ---------------- generic BMxBN MFMA GEMM body (bf16 MFMA core) ------------
// C[m,n] = epilogue( sum_k A[m,k] * B'[n,k] + bias[n] )
// AMODE 0: A bf16 scratch [M,K]
// AMODE 1: A f32 [M,K] (cvt in staging)
// AMODE 2: A row n = concat(inputsF[n], aggin[n]) f32->bf16 (K=512)
// AMODE 3: A row e = relu(U[sidx[e]][k] + V[ridx[e]][k] + b1[k]), U/V bf16 (K=512)
// BMODE 0: B' = Bt f32 [N,K]
// BMODE 1: B' row n = msg_W1[n&511][ (n>>9)*256 .. +K ]  (split W1 halves)
// EPI 0: +bias, relu, store bf16 Cout[M,N]
// EPI 1: +bias, relu, atomicAdd fp32 into aggout[rIdx[row]*256+n]
// EPI 2: +bias, add f32 residual inputsF[m,n], store f32 OutF (N==256)
// EPI 3: raw f32 store OutF[M,N] (no bias)
// EPI 4: raw bf16 store Cout[M,N] (no bias)
template<int BM, int BN, int AMODE, int BMODE, int EPI>
__device__ __forceinline__ void gemm_body(
    const bf16* __restrict__ A, const float* __restrict__ Af,
    const float* __restrict__ Bt, const float* __restrict__ bias,
    bf16* __restrict__ Cout, float* __restrict__ OutF,
    const float* __restrict__ inputsF, const bf16* __restrict__ UVb,
    const float* __restrict__ b1v, const int* __restrict__ sidx,
    const int* __restrict__ ridx, const float* __restrict__ aggin,
    float* __restrict__ aggout, int M, int N, int K, int bx, int by)
{
    constexpr int BK = 32;
    constexpr int PA = BM / 64;   // A staging passes (16B/thread each)
    constexpr int PB = BN / 64;
    constexpr int MI = BM / 32;   // per-wave 16-tiles in M
    constexpr int NJ = BN / 32;   // per-wave 16-tiles in N
    __shared__ bf16 As[BM * BK];
    __shared__ bf16 Bs[BN * BK];
    __shared__ int sIdx[BM];
    __shared__ int rIdx[BM];

    const int t = threadIdx.x;
    const int m0 = by * BM;
    const int n0 = bx * BN;

    if constexpr (AMODE == 3) {
        if (t < BM) {
            sIdx[t] = sidx[m0 + t] & (NODES - 1);   // OOB structurally impossible
            rIdx[t] = ridx[m0 + t] & (NODES - 1);
        }
        __syncthreads();
    }

    // staging: thread t covers LDS row (p*64 + t/4), 16B bf16 chunk (t%4)
    const int sr = t >> 2;
    const int sc = t & 3;

    uint4 ra[PA], rb[PB];

    auto loadTiles = [&](int kt) {
        const int kk = kt * BK + sc * 8;   // element column within K
#pragma unroll
        for (int p = 0; p < PA; ++p) {
            const int row = p * 64 + sr;
            if constexpr (AMODE == 0) {
                ra[p] = *(const uint4*)(A + (size_t)(m0 + row) * K + kk);
            } else if constexpr (AMODE == 1) {
                ra[p] = cvt8(Af + (size_t)(m0 + row) * K + kk);
            } else if constexpr (AMODE == 2) {
                const float* src = (kk < 256)
                    ? (inputsF + (size_t)(m0 + row) * 256 + kk)
                    : (aggin + (size_t)(m0 + row) * 256 + (kk - 256));
                ra[p] = cvt8(src);
            } else {
                union { uint4 q; unsigned short h[8]; } uu, vv;
                uu.q = *(const uint4*)(UVb + (size_t)sIdx[row] * 1024 + kk);
                vv.q = *(const uint4*)(UVb + (size_t)rIdx[row] * 1024 + 512 + kk);
                const float4* c = (const float4*)(b1v + kk);
                float4 c0 = c[0], c1 = c[1];
                const float cf[8] = {c0.x, c0.y, c0.z, c0.w, c1.x, c1.y, c1.z, c1.w};
                union { uint4 q; bf16 h[8]; } pk;
#pragma unroll
                for (int e = 0; e < 8; ++e) {
                    union { unsigned int u; float f; } a2, b2;
                    a2.u = (unsigned int)uu.h[e] << 16;
                    b2.u = (unsigned int)vv.h[e] << 16;
                    pk.h[e] = __float2bfloat16(fmaxf(a2.f + b2.f + cf[e], 0.f));
                }
                ra[p] = pk.q;
            }
        }
#pragma unroll
        for (int p = 0; p < PB; ++p) {
            const int row = p * 64 + sr;
            if constexpr (BMODE == 0) {
                rb[p] = cvt8(Bt + (size_t)(n0 + row) * K + kk);
            } else {
                const int n = n0 + row;
                rb[p] = cvt8(Bt + (size_t)(n & 511) * 512 + (n >> 9) * 256 + kk);
            }
        }
    };

    const int wv = t >> 6;
    const int lane = t & 63;
    const int wm = wv >> 1, wn = wv & 1;   // wave covers (BM/2)x(BN/2)
    const int r16 = lane & 15, q = lane >> 4;

    floatx4 acc[MI][NJ] = {};

    loadTiles(0);
    const int KT = K / BK;
    for (int kt = 0; kt < KT; ++kt) {
        __syncthreads();
#pragma unroll
        for (int p = 0; p < PA; ++p)
            *(uint4*)(&As[(p * 64 + sr) * BK + sc * 8]) = ra[p];
#pragma unroll
        for (int p = 0; p < PB; ++p)
            *(uint4*)(&Bs[(p * 64 + sr) * BK + sc * 8]) = rb[p];
        __syncthreads();
        if (kt + 1 < KT) loadTiles(kt + 1);   // overlap next-tile loads with MFMA

        bf16x8 af[MI], bfr[NJ];
#pragma unroll
        for (int i = 0; i < MI; ++i)
            af[i] = *(const bf16x8*)(&As[(wm * (BM / 2) + i * 16 + r16) * BK + q * 8]);
#pragma unroll
        for (int j = 0; j < NJ; ++j)
            bfr[j] = *(const bf16x8*)(&Bs[(wn * (BN / 2) + j * 16 + r16) * BK + q * 8]);
#pragma unroll
        for (int i = 0; i < MI; ++i)
#pragma unroll
            for (int j = 0; j < NJ; ++j)
                acc[i][j] = __builtin_amdgcn_mfma_f32_16x16x32_bf16(af[i], bfr[j], acc[i][j], 0, 0, 0);
    }

    float bv[NJ];
#pragma unroll
    for (int j = 0; j < NJ; ++j)
        bv[j] = (EPI == 3 || EPI == 4) ? 0.f : bias[n0 + wn * (BN / 2) + j * 16 + r16];

    // C/D layout: col = lane&15, row = q*4 + r (verified m89/m91)
#pragma unroll
    for (int i = 0; i < MI; ++i) {
        const int lr = wm * (BM / 2) + i * 16 + q * 4;
        const int rbase = m0 + lr;
#pragma unroll
        for (int j = 0; j < NJ; ++j) {
            const int gc = n0 + wn * (BN / 2) + j * 16 + r16;
#pragma unroll
            for (int r = 0; r < 4; ++r) {
                float v = acc[i][j][r] + bv[j];
                const int gr = rbase + r;
                if constexpr (EPI == 0) {
                    v = fmaxf(v, 0.0f);
                    Cout[(size_t)gr * N + gc] = __float2bfloat16(v);
                } else if constexpr (EPI == 1) {
                    v = fmaxf(v, 0.0f);
                    atomicAdd(&aggout[(size_t)rIdx[lr + r] * 256 + gc], v);
                } else if constexpr (EPI == 2) {
                    OutF[(size_t)gr * 256 + gc] = inputsF[(size_t)gr * 256 + gc] + v;
                } else if constexpr (EPI == 3) {
                    OutF[(size_t)gr * N + gc] = v;
                } else {
                    Cout[(size_t)gr * N + gc] = __float2bfloat16(v);
                }
            }
        }
    }
}

template<int BM, int BN, int AMODE, int BMODE, int EPI>
__global__ __launch_bounds__(256, 2) void gemm_k(
    const bf16* __restrict__ A, const float* __restrict__ Af,
    const float* __restrict__ Bt, const float* __restrict__ bias,
    bf16* __restrict__ Cout, float* __restrict__ OutF,
    const float* __restrict__ inputsF, const bf16* __restrict__ UVb,
    const float* __restrict__ b1v, const int* __restrict__ sidx,
    const int* __restrict__ ridx, const float* __restrict__ aggin,
    float* __restrict__ aggout, int M, int N, int K)
{
    gemm_body<BM, BN, AMODE, BMODE, EPI>(A, Af, Bt, bias, Cout, OutF, inputsF,
        UVb, b1v, sidx, ridx, aggin, aggout, M, N, K, blockIdx.x, blockIdx.y);
}

// ---------------- fat front kernel: extract + zero + UV GEMM ---------------
// blocks [0,16384): one-hot index extraction (one wave per row, early exit)
// blocks [16384,16896): zero agg (2 MB)
// blocks [16896,17408): UV(bf16) = inputs @ [W1_left|W1_right]^T (64x64 tiles)
__global__ __launch_bounds__(256) void fat_pre(
    const float* __restrict__ rel_rec, const float* __restrict__ rel_send,
    int* __restrict__ recv_idx, int* __restrict__ send_idx,
    float4* __restrict__ agg, const float* __restrict__ inputs,
    const float* __restrict__ msg_W1, bf16* __restrict__ UVb)
{
    const int b = blockIdx.x;
    if (b < 16384) {
        const int half = b >> 13;          // 0: rel_rec, 1: rel_send
        const int rb = b & 8191;
        const float* mat = half ? rel_send : rel_rec;
        int* out = half ? send_idx : recv_idx;
        const int w = threadIdx.x >> 6;
        const int lane = threadIdx.x & 63;
        const int row = rb * 4 + w;        // 0..32767
        if (lane == 0) out[row] = 0;       // defensive init
        const uint4* base = (const uint4*)(mat + (size_t)row * NODES);
        for (int p = 0; p < 8; ++p) {
            uint4 v = base[p * 64 + lane];
            const bool hit = (v.x | v.y | v.z | v.w) != 0u;
            if (hit) {
                int e = v.x ? 0 : (v.y ? 1 : (v.z ? 2 : 3));
                out[row] = p * 256 + lane * 4 + e;
            }
            if (__any(hit)) break;         // wave early exit (avg ~4.5/8 passes)
        }
    } else if (b < 16896) {
        agg[(size_t)(b - 16384) * 256 + threadIdx.x] = float4{0.f, 0.f, 0.f, 0.f};
    } else {
        const int g = b - 16896;           // 512 blocks: 16 x-tiles, 32 y-tiles
        gemm_body<64, 64, 1, 1, 4>(nullptr, inputs, msg_W1, nullptr, UVb, nullptr,
            nullptr, nullptr, nullptr, nullptr, nullptr, nullptr, nullptr,
            NODES, 1024, 256, g & 15, g >> 4);
    }
}

extern "C" void kernel_launch(void* const* d_in, const int* in_sizes, int n_in,
                              void* d_out, int out_size, void* d_ws, size_t ws_size,
                              hipStream_t stream) {
    const float* inputs   = (const float*)d_in[0];
    const float* rel_rec  = (const float*)d_in[1];
    const float* rel_send = (const float*)d_in[2];
    const float* msg_W1   = (const float*)d_in[3];
    const float* msg_b1   = (const float*)d_in[4];
    const float* msg_W2   = (const float*)d_in[5];
    const float* msg_b2   = (const float*)d_in[6];
    const float* out_W1   = (const float*)d_in[7];
    const float* out_b1   = (const float*)d_in[8];
    const float* out_W2   = (const float*)d_in[9];
    const float* out_b2   = (const float*)d_in[10];
    const float* out_W3   = (const float*)d_in[11];
    const float* out_b3   = (const float*)d_in[12];

    // workspace layout (~10.4 MB total)
    char* ws = (char*)d_ws;
    int*   recv_idx = (int*)(ws + 0);            // 128 KB
    int*   send_idx = (int*)(ws + 131072);       // 128 KB
    float* agg      = (float*)(ws + 262144);     // 2 MB fp32 [2048,256]
    bf16*  UVb      = (bf16*)(ws + 2359296);     // 4 MB bf16 [2048,1024] (U|V)
    bf16*  g1       = (bf16*)(ws + 6553600);     // 2 MB bf16 [2048,512]
    bf16*  g2       = (bf16*)(ws + 8650752);     // 2 MB bf16 [2048,512]
    if (ws_size < (size_t)11 * 1024 * 1024) return;  // fail loudly, not fault

    // 1) fused: index extraction + agg zeroing + UV GEMM (all independent)
    fat_pre<<<17408, 256, 0, stream>>>(rel_rec, rel_send, recv_idx, send_idx,
                                       (float4*)agg, inputs, msg_W1, UVb);

    // 2) fused edge layer-2 + scatter, single N-tile (each edge gathered ONCE):
    //    agg[recv[e]] += relu( relu(U[send[e]]+V[recv[e]]+b1) @ W2^T + b2 )
    gemm_k<64, 256, 3, 0, 1><<<dim3(1, 512), 256, 0, stream>>>(
        nullptr, nullptr, msg_W2, msg_b2, nullptr, nullptr,
        nullptr, UVb, msg_b1, send_idx, recv_idx, nullptr, agg,
        EDGES, 256, 512);

    // 3) node MLP layer 1 (64-tile, 256 blocks): g1 = relu(concat(inputs,agg)@W1^T+b1)
    gemm_k<64, 64, 2, 0, 0><<<dim3(8, 32), 256, 0, stream>>>(
        nullptr, nullptr, out_W1, out_b1, g1, nullptr,
        inputs, nullptr, nullptr, nullptr, nullptr, agg, nullptr,
        NODES, 512, 512);

    // 4) node MLP layer 2 (64-tile, 256 blocks): g2 = relu(g1 @ W2^T + b2)
    gemm_k<64, 64, 0, 0, 0><<<dim3(8, 32), 256, 0, stream>>>(
        g1, nullptr, out_W2, out_b2, g2, nullptr,
        nullptr, nullptr, nullptr, nullptr, nullptr, nullptr, nullptr,
        NODES, 512, 512);

    // 5) node MLP layer 3 + residual (64-tile, 128 blocks):
    //    out = inputs + (g2 @ W3^T + b3)
    gemm_k<64, 64, 0, 0, 2><<<dim3(4, 32), 256, 0, stream>>>(
        g2, nullptr, out_W3, out_b3, nullptr, (float*)d_out,
        inputs, nullptr, nullptr, nullptr, nullptr, nullptr, nullptr,
        NODES, 256, 512);
}

// Round 8
// 593.265 us; speedup vs baseline: 1.0269x; 1.0269x over previous
//
#include <hip/hip_runtime.h>
#include <hip/hip_bf16.h>
#include <stdint.h>

using bf16 = __hip_bfloat16;
typedef short bf16x8 __attribute__((ext_vector_type(8)));
typedef float floatx4 __attribute__((ext_vector_type(4)));

static constexpr int NODES = 2048;
static constexpr int EDGES = 32768;

// pack 8 consecutive f32 -> 8 bf16 (rne) as uint4
__device__ inline uint4 cvt8(const float* __restrict__ p) {
    const float4* f = (const float4*)p;
    float4 a = f[0], b = f[1];
    union { uint4 u; bf16 h[8]; } pk;
    pk.h[0] = __float2bfloat16(a.x); pk.h[1] = __float2bfloat16(a.y);
    pk.h[2] = __float2bfloat16(a.z); pk.h[3] = __float2bfloat16(a.w);
    pk.h[4] = __float2bfloat16(b.x); pk.h[5] = __float2bfloat16(b.y);
    pk.h[6] = __float2bfloat16(b.z); pk.h[7] = __float2bfloat16(b.w);
    return pk.u;
}

// ---------------- generic BMxBN MFMA GEMM body (bf16 MFMA core) ------------
// C[m,n] = epilogue( sum_k A[m,k] * B'[n,k] + bias[n] )
// AMODE 0: A bf16 scratch [M,K]
// AMODE 1: A f32 [M,K] (cvt in staging)
// AMODE 2: A row n = concat(inputsF[n], aggin[n]) f32->bf16 (K=512)
// AMODE 3: A row e = relu(U[sidx[e]][k] + V[ridx[e]][k] + b1[k]), U/V bf16 (K=512)
// BMODE 0: B' = Bt f32 [N,K]
// BMODE 1: B' row n = msg_W1[n&511][ (n>>9)*256 .. +K ]  (split W1 halves)
// EPI 0: +bias, relu, store bf16 Cout[M,N]
// EPI 1: +bias, relu, atomicAdd fp32 into aggout[rIdx[row]*256+n]
// EPI 2: +bias, add f32 residual inputsF[m,n], store f32 OutF (N==256)
// EPI 3: raw f32 store OutF[M,N] (no bias)
// EPI 4: raw bf16 store Cout[M,N] (no bias)
template<int BM, int BN, int AMODE, int BMODE, int EPI>
__device__ __forceinline__ void gemm_body(
    const bf16* __restrict__ A, const float* __restrict__ Af,
    const float* __restrict__ Bt, const float* __restrict__ bias,
    bf16* __restrict__ Cout, float* __restrict__ OutF,
    const float* __restrict__ inputsF, const bf16* __restrict__ UVb,
    const float* __restrict__ b1v, const int* __restrict__ sidx,
    const int* __restrict__ ridx, const float* __restrict__ aggin,
    float* __restrict__ aggout, int M, int N, int K, int bx, int by)
{
    constexpr int BK = 32;
    constexpr int PA = BM / 64;   // A staging passes (16B/thread each)
    constexpr int PB = BN / 64;
    constexpr int MI = BM / 32;   // per-wave 16-tiles in M
    constexpr int NJ = BN / 32;   // per-wave 16-tiles in N
    __shared__ bf16 As[BM * BK];
    __shared__ bf16 Bs[BN * BK];
    __shared__ int sIdx[BM];
    __shared__ int rIdx[BM];

    const int t = threadIdx.x;
    const int m0 = by * BM;
    const int n0 = bx * BN;

    if constexpr (AMODE == 3) {
        if (t < BM) {
            sIdx[t] = sidx[m0 + t] & (NODES - 1);   // OOB structurally impossible
            rIdx[t] = ridx[m0 + t] & (NODES - 1);
        }
        __syncthreads();
    }

    // staging: thread t covers LDS row (p*64 + t/4), 16B bf16 chunk (t%4)
    const int sr = t >> 2;
    const int sc = t & 3;

    uint4 ra[PA], rb[PB];

    auto loadTiles = [&](int kt) {
        const int kk = kt * BK + sc * 8;   // element column within K
#pragma unroll
        for (int p = 0; p < PA; ++p) {
            const int row = p * 64 + sr;
            if constexpr (AMODE == 0) {
                ra[p] = *(const uint4*)(A + (size_t)(m0 + row) * K + kk);
            } else if constexpr (AMODE == 1) {
                ra[p] = cvt8(Af + (size_t)(m0 + row) * K + kk);
            } else if constexpr (AMODE == 2) {
                const float* src = (kk < 256)
                    ? (inputsF + (size_t)(m0 + row) * 256 + kk)
                    : (aggin + (size_t)(m0 + row) * 256 + (kk - 256));
                ra[p] = cvt8(src);
            } else {
                union { uint4 q; unsigned short h[8]; } uu, vv;
                uu.q = *(const uint4*)(UVb + (size_t)sIdx[row] * 1024 + kk);
                vv.q = *(const uint4*)(UVb + (size_t)rIdx[row] * 1024 + 512 + kk);
                const float4* c = (const float4*)(b1v + kk);
                float4 c0 = c[0], c1 = c[1];
                const float cf[8] = {c0.x, c0.y, c0.z, c0.w, c1.x, c1.y, c1.z, c1.w};
                union { uint4 q; bf16 h[8]; } pk;
#pragma unroll
                for (int e = 0; e < 8; ++e) {
                    union { unsigned int u; float f; } a2, b2;
                    a2.u = (unsigned int)uu.h[e] << 16;
                    b2.u = (unsigned int)vv.h[e] << 16;
                    pk.h[e] = __float2bfloat16(fmaxf(a2.f + b2.f + cf[e], 0.f));
                }
                ra[p] = pk.q;
            }
        }
#pragma unroll
        for (int p = 0; p < PB; ++p) {
            const int row = p * 64 + sr;
            if constexpr (BMODE == 0) {
                rb[p] = cvt8(Bt + (size_t)(n0 + row) * K + kk);
            } else {
                const int n = n0 + row;
                rb[p] = cvt8(Bt + (size_t)(n & 511) * 512 + (n >> 9) * 256 + kk);
            }
        }
    };

    const int wv = t >> 6;
    const int lane = t & 63;
    const int wm = wv >> 1, wn = wv & 1;   // wave covers (BM/2)x(BN/2)
    const int r16 = lane & 15, q = lane >> 4;

    floatx4 acc[MI][NJ] = {};

    loadTiles(0);
    const int KT = K / BK;
    for (int kt = 0; kt < KT; ++kt) {
        __syncthreads();
#pragma unroll
        for (int p = 0; p < PA; ++p)
            *(uint4*)(&As[(p * 64 + sr) * BK + sc * 8]) = ra[p];
#pragma unroll
        for (int p = 0; p < PB; ++p)
            *(uint4*)(&Bs[(p * 64 + sr) * BK + sc * 8]) = rb[p];
        __syncthreads();
        if (kt + 1 < KT) loadTiles(kt + 1);   // overlap next-tile loads with MFMA

        bf16x8 af[MI], bfr[NJ];
#pragma unroll
        for (int i = 0; i < MI; ++i)
            af[i] = *(const bf16x8*)(&As[(wm * (BM / 2) + i * 16 + r16) * BK + q * 8]);
#pragma unroll
        for (int j = 0; j < NJ; ++j)
            bfr[j] = *(const bf16x8*)(&Bs[(wn * (BN / 2) + j * 16 + r16) * BK + q * 8]);
#pragma unroll
        for (int i = 0; i < MI; ++i)
#pragma unroll
            for (int j = 0; j < NJ; ++j)
                acc[i][j] = __builtin_amdgcn_mfma_f32_16x16x32_bf16(af[i], bfr[j], acc[i][j], 0, 0, 0);
    }

    float bv[NJ];
#pragma unroll
    for (int j = 0; j < NJ; ++j)
        bv[j] = (EPI == 3 || EPI == 4) ? 0.f : bias[n0 + wn * (BN / 2) + j * 16 + r16];

    // C/D layout: col = lane&15, row = q*4 + r (verified m89/m91)
#pragma unroll
    for (int i = 0; i < MI; ++i) {
        const int lr = wm * (BM / 2) + i * 16 + q * 4;
        const int rbase = m0 + lr;
#pragma unroll
        for (int j = 0; j < NJ; ++j) {
            const int gc = n0 + wn * (BN / 2) + j * 16 + r16;
#pragma unroll
            for (int r = 0; r < 4; ++r) {
                float v = acc[i][j][r] + bv[j];
                const int gr = rbase + r;
                if constexpr (EPI == 0) {
                    v = fmaxf(v, 0.0f);
                    Cout[(size_t)gr * N + gc] = __float2bfloat16(v);
                } else if constexpr (EPI == 1) {
                    v = fmaxf(v, 0.0f);
                    atomicAdd(&aggout[(size_t)rIdx[lr + r] * 256 + gc], v);
                } else if constexpr (EPI == 2) {
                    OutF[(size_t)gr * 256 + gc] = inputsF[(size_t)gr * 256 + gc] + v;
                } else if constexpr (EPI == 3) {
                    OutF[(size_t)gr * N + gc] = v;
                } else {
                    Cout[(size_t)gr * N + gc] = __float2bfloat16(v);
                }
            }
        }
    }
}

template<int BM, int BN, int AMODE, int BMODE, int EPI>
__global__ __launch_bounds__(256, 2) void gemm_k(
    const bf16* __restrict__ A, const float* __restrict__ Af,
    const float* __restrict__ Bt, const float* __restrict__ bias,
    bf16* __restrict__ Cout, float* __restrict__ OutF,
    const float* __restrict__ inputsF, const bf16* __restrict__ UVb,
    const float* __restrict__ b1v, const int* __restrict__ sidx,
    const int* __restrict__ ridx, const float* __restrict__ aggin,
    float* __restrict__ aggout, int M, int N, int K)
{
    gemm_body<BM, BN, AMODE, BMODE, EPI>(A, Af, Bt, bias, Cout, OutF, inputsF,
        UVb, b1v, sidx, ridx, aggin, aggout, M, N, K, blockIdx.x, blockIdx.y);
}

// ---------------- fat front kernel: UV GEMM + zero + extract ---------------
// blocks [0,512):      UV(bf16) = inputs @ [W1_left|W1_right]^T (64x64 tiles)
//                      -- FIRST so they start before the extract flood
// blocks [512,1024):   zero agg (2 MB)
// blocks [1024,17408): one-hot index extraction (one wave per row, early exit)
// __launch_bounds__(256,8): cap 64 VGPR so the extract waves keep 8 waves/SIMD
// (extract is HBM-latency-bound, 1 load in flight/wave: occupancy IS bandwidth)
__global__ __launch_bounds__(256, 8) void fat_pre(
    const float* __restrict__ rel_rec, const float* __restrict__ rel_send,
    int* __restrict__ recv_idx, int* __restrict__ send_idx,
    float4* __restrict__ agg, const float* __restrict__ inputs,
    const float* __restrict__ msg_W1, bf16* __restrict__ UVb)
{
    const int b = blockIdx.x;
    if (b < 512) {
        gemm_body<64, 64, 1, 1, 4>(nullptr, inputs, msg_W1, nullptr, UVb, nullptr,
            nullptr, nullptr, nullptr, nullptr, nullptr, nullptr, nullptr,
            NODES, 1024, 256, b & 15, b >> 4);
    } else if (b < 1024) {
        agg[(size_t)(b - 512) * 256 + threadIdx.x] = float4{0.f, 0.f, 0.f, 0.f};
    } else {
        const int eb = b - 1024;
        const int half = eb >> 13;         // 0: rel_rec, 1: rel_send
        const int rb = eb & 8191;
        const float* mat = half ? rel_send : rel_rec;
        int* out = half ? send_idx : recv_idx;
        const int w = threadIdx.x >> 6;
        const int lane = threadIdx.x & 63;
        const int row = rb * 4 + w;        // 0..32767
        if (lane == 0) out[row] = 0;       // defensive init
        const uint4* base = (const uint4*)(mat + (size_t)row * NODES);
        for (int p = 0; p < 8; ++p) {
            uint4 v = base[p * 64 + lane];
            const bool hit = (v.x | v.y | v.z | v.w) != 0u;
            if (hit) {
                int e = v.x ? 0 : (v.y ? 1 : (v.z ? 2 : 3));
                out[row] = p * 256 + lane * 4 + e;
            }
            if (__any(hit)) break;         // wave early exit (avg ~4.5/8 passes)
        }
    }
}

extern "C" void kernel_launch(void* const* d_in, const int* in_sizes, int n_in,
                              void* d_out, int out_size, void* d_ws, size_t ws_size,
                              hipStream_t stream) {
    const float* inputs   = (const float*)d_in[0];
    const float* rel_rec  = (const float*)d_in[1];
    const float* rel_send = (const float*)d_in[2];
    const float* msg_W1   = (const float*)d_in[3];
    const float* msg_b1   = (const float*)d_in[4];
    const float* msg_W2   = (const float*)d_in[5];
    const float* msg_b2   = (const float*)d_in[6];
    const float* out_W1   = (const float*)d_in[7];
    const float* out_b1   = (const float*)d_in[8];
    const float* out_W2   = (const float*)d_in[9];
    const float* out_b2   = (const float*)d_in[10];
    const float* out_W3   = (const float*)d_in[11];
    const float* out_b3   = (const float*)d_in[12];

    // workspace layout (~10.4 MB total)
    char* ws = (char*)d_ws;
    int*   recv_idx = (int*)(ws + 0);            // 128 KB
    int*   send_idx = (int*)(ws + 131072);       // 128 KB
    float* agg      = (float*)(ws + 262144);     // 2 MB fp32 [2048,256]
    bf16*  UVb      = (bf16*)(ws + 2359296);     // 4 MB bf16 [2048,1024] (U|V)
    bf16*  g1       = (bf16*)(ws + 6553600);     // 2 MB bf16 [2048,512]
    bf16*  g2       = (bf16*)(ws + 8650752);     // 2 MB bf16 [2048,512]
    if (ws_size < (size_t)11 * 1024 * 1024) return;  // fail loudly, not fault

    // 1) fused: UV GEMM (first!) + agg zeroing + index extraction
    fat_pre<<<17408, 256, 0, stream>>>(rel_rec, rel_send, recv_idx, send_idx,
                                       (float4*)agg, inputs, msg_W1, UVb);

    // 2) fused edge layer-2 + scatter (R6-measured-best 128x128 tile):
    //    agg[recv[e]] += relu( relu(U[send[e]]+V[recv[e]]+b1) @ W2^T + b2 )
    gemm_k<128, 128, 3, 0, 1><<<dim3(2, 256), 256, 0, stream>>>(
        nullptr, nullptr, msg_W2, msg_b2, nullptr, nullptr,
        nullptr, UVb, msg_b1, send_idx, recv_idx, nullptr, agg,
        EDGES, 256, 512);

    // 3) node MLP layer 1 (64-tile, 256 blocks): g1 = relu(concat(inputs,agg)@W1^T+b1)
    gemm_k<64, 64, 2, 0, 0><<<dim3(8, 32), 256, 0, stream>>>(
        nullptr, nullptr, out_W1, out_b1, g1, nullptr,
        inputs, nullptr, nullptr, nullptr, nullptr, agg, nullptr,
        NODES, 512, 512);

    // 4) node MLP layer 2 (64-tile, 256 blocks): g2 = relu(g1 @ W2^T + b2)
    gemm_k<64, 64, 0, 0, 0><<<dim3(8, 32), 256, 0, stream>>>(
        g1, nullptr, out_W2, out_b2, g2, nullptr,
        nullptr, nullptr, nullptr, nullptr, nullptr, nullptr, nullptr,
        NODES, 512, 512);

    // 5) node MLP layer 3 + residual (64-tile, 128 blocks):
    //    out = inputs + (g2 @ W3^T + b3)
    gemm_k<64, 64, 0, 0, 2><<<dim3(4, 32), 256, 0, stream>>>(
        g2, nullptr, out_W3, out_b3, nullptr, (float*)d_out,
        inputs, nullptr, nullptr, nullptr, nullptr, nullptr, nullptr,
        NODES, 256, 512);
}